// Round 1
// baseline (310.218 us; speedup 1.0000x reference)
//
#include <hip/hip_runtime.h>
#include <math.h>

// Problem constants (fixed by setup_inputs).
constexpr int Bb = 32;
constexpr int Nn = 16384;
constexpr int Kk = 64;
constexpr int NCHUNK = 8;                 // N-chunks per (set,batch)
constexpr int ROWS = Nn / NCHUNK;         // 2048 rows per chunk
constexpr int NBLK1 = 2 * Bb * NCHUNK;    // 512 blocks
#define EPSF 1e-8f

// ---------------------------------------------------------------------------
// Kernel 1: per-chunk partial sums.
// Block = 256 threads (4 waves). Wave processes 4 consecutive rows per
// iteration: lane = sub*16 + kq; lane reads float4 gamma[b, n+sub, 4kq..4kq+3]
// -> the wave's 64 lanes read 4 full contiguous rows (1 KiB) per instruction.
// Each lane accumulates (sum_g, sum_g*px, sum_g*py, sum_g*pz) for 4 clusters.
// ---------------------------------------------------------------------------
__global__ __launch_bounds__(256) void gmm_partial_kernel(
    const float* __restrict__ points_x, const float* __restrict__ points_y,
    const float* __restrict__ gamma_x,  const float* __restrict__ gamma_y,
    float4* __restrict__ ws4)
{
    const int bx    = blockIdx.x;             // 0..511
    const int chunk = bx & (NCHUNK - 1);
    const int combo = bx >> 3;                // 0..63
    const int s     = combo >> 5;             // set: 0=x, 1=y
    const int b     = combo & 31;

    const float* __restrict__ gbase = (s ? gamma_y : gamma_x) + (size_t)b * Nn * Kk;
    const float* __restrict__ pbase = (s ? points_y : points_x) + (size_t)b * Nn * 3;

    const int tid  = threadIdx.x;
    const int wave = tid >> 6;
    const int lane = tid & 63;
    const int sub  = lane >> 4;   // which of 4 rows this lane covers
    const int kq   = lane & 15;   // cluster quad: clusters 4kq .. 4kq+3

    float a0=0.f,a1=0.f,a2=0.f,a3=0.f;   // sum gamma
    float x0=0.f,x1=0.f,x2=0.f,x3=0.f;   // sum gamma*px
    float y0=0.f,y1=0.f,y2=0.f,y3=0.f;   // sum gamma*py
    float z0=0.f,z1=0.f,z2=0.f,z3=0.f;   // sum gamma*pz

    const int row0 = chunk * ROWS;
    for (int r = wave * 4; r < ROWS; r += 16) {
        const int n = row0 + r + sub;
        const float4 g = *reinterpret_cast<const float4*>(
            gbase + (size_t)n * Kk + (kq << 2));
        const float ppx = pbase[n * 3 + 0];
        const float ppy = pbase[n * 3 + 1];
        const float ppz = pbase[n * 3 + 2];
        a0 += g.x; x0 = fmaf(g.x, ppx, x0); y0 = fmaf(g.x, ppy, y0); z0 = fmaf(g.x, ppz, z0);
        a1 += g.y; x1 = fmaf(g.y, ppx, x1); y1 = fmaf(g.y, ppy, y1); z1 = fmaf(g.y, ppz, z1);
        a2 += g.z; x2 = fmaf(g.z, ppx, x2); y2 = fmaf(g.z, ppy, y2); z2 = fmaf(g.z, ppz, z2);
        a3 += g.w; x3 = fmaf(g.w, ppx, x3); y3 = fmaf(g.w, ppy, y3); z3 = fmaf(g.w, ppz, z3);
    }

    // Reduce across the 4 sub-row groups (lanes l, l^16, l^32, l^48).
#define RED2(v) { v += __shfl_xor(v, 16); v += __shfl_xor(v, 32); }
    RED2(a0) RED2(a1) RED2(a2) RED2(a3)
    RED2(x0) RED2(x1) RED2(x2) RED2(x3)
    RED2(y0) RED2(y1) RED2(y2) RED2(y3)
    RED2(z0) RED2(z1) RED2(z2) RED2(z3)
#undef RED2

    __shared__ float4 lds[4][Kk];
    if (lane < 16) {  // sub==0 group holds the wave totals (all do, pick one)
        lds[wave][kq * 4 + 0] = make_float4(a0, x0, y0, z0);
        lds[wave][kq * 4 + 1] = make_float4(a1, x1, y1, z1);
        lds[wave][kq * 4 + 2] = make_float4(a2, x2, y2, z2);
        lds[wave][kq * 4 + 3] = make_float4(a3, x3, y3, z3);
    }
    __syncthreads();
    if (tid < Kk) {
        float4 v0 = lds[0][tid], v1 = lds[1][tid], v2 = lds[2][tid], v3 = lds[3][tid];
        float4 o;
        o.x = v0.x + v1.x + v2.x + v3.x;
        o.y = v0.y + v1.y + v2.y + v3.y;
        o.z = v0.z + v1.z + v2.z + v3.z;
        o.w = v0.w + v1.w + v2.w + v3.w;
        ws4[(size_t)bx * Kk + tid] = o;   // [combo][chunk][k] = (pi_sum, wx, wy, wz)
    }
}

// ---------------------------------------------------------------------------
// Kernel 2: per-batch finalize. 32 blocks x 64 lanes (1 wave). Lane k owns
// cluster k; wave-level butterfly reductions over K; lane 0 does the 3x3 SVD.
// ---------------------------------------------------------------------------
__device__ __forceinline__ float wred64(float v) {
    v += __shfl_xor(v, 1);  v += __shfl_xor(v, 2);  v += __shfl_xor(v, 4);
    v += __shfl_xor(v, 8);  v += __shfl_xor(v, 16); v += __shfl_xor(v, 32);
    return v;
}

__global__ __launch_bounds__(64) void gmm_finalize_kernel(
    const float4* __restrict__ ws4, float* __restrict__ out)
{
    const int b = blockIdx.x;   // batch
    const int k = threadIdx.x;  // cluster

    float4 s0 = make_float4(0.f, 0.f, 0.f, 0.f);
    float4 s1 = make_float4(0.f, 0.f, 0.f, 0.f);
    for (int c = 0; c < NCHUNK; ++c) {
        float4 t0 = ws4[((size_t)(b * NCHUNK + c)) * Kk + k];            // set x
        float4 t1 = ws4[((size_t)((Bb + b) * NCHUNK + c)) * Kk + k];     // set y
        s0.x += t0.x; s0.y += t0.y; s0.z += t0.z; s0.w += t0.w;
        s1.x += t1.x; s1.y += t1.y; s1.z += t1.z; s1.w += t1.w;
    }

    const float pix = s0.x * (1.f / Nn);
    const float piy = s1.x * (1.f / Nn);
    const float idx_ = 1.f / (pix + EPSF);
    const float idy_ = 1.f / (piy + EPSF);
    const float mux0 = s0.y * idx_, mux1 = s0.z * idx_, mux2 = s0.w * idx_;
    const float muy0 = s1.y * idy_, muy1 = s1.z * idy_, muy2 = s1.w * idy_;
    const float w = pix * piy;

    // centroid reductions
    const float wsum = wred64(w) + EPSF;
    const float cs0 = wred64(w * mux0) / wsum;
    const float cs1 = wred64(w * mux1) / wsum;
    const float cs2 = wred64(w * mux2) / wsum;
    const float ct0 = wred64(w * muy0) / wsum;
    const float ct1 = wred64(w * muy1) / wsum;
    const float ct2 = wred64(w * muy2) / wsum;

    const float sx0 = mux0 - cs0, sx1 = mux1 - cs1, sx2 = mux2 - cs2;
    const float tx0 = muy0 - ct0, tx1 = muy1 - ct1, tx2 = muy2 - ct2;

    // H_ij = sum_k w * s_i * t_j
    float H[3][3];
    H[0][0] = wred64(w * sx0 * tx0); H[0][1] = wred64(w * sx0 * tx1); H[0][2] = wred64(w * sx0 * tx2);
    H[1][0] = wred64(w * sx1 * tx0); H[1][1] = wred64(w * sx1 * tx1); H[1][2] = wred64(w * sx1 * tx2);
    H[2][0] = wred64(w * sx2 * tx0); H[2][1] = wred64(w * sx2 * tx1); H[2][2] = wred64(w * sx2 * tx2);

    if (k != 0) return;

    float R_[3][3];
    float tv[3];

    float mx = 0.f;
    for (int i = 0; i < 3; ++i)
        for (int j = 0; j < 3; ++j) mx = fmaxf(mx, fabsf(H[i][j]));

    if (mx < 1e-35f) {
        // degenerate: H ~ 0 -> R = I
        for (int i = 0; i < 3; ++i)
            for (int j = 0; j < 3; ++j) R_[i][j] = (i == j) ? 1.f : 0.f;
        tv[0] = ct0 - cs0; tv[1] = ct1 - cs1; tv[2] = ct2 - cs2;
    } else {
        const float inv = 1.f / mx;
        float h[3][3];
        for (int i = 0; i < 3; ++i)
            for (int j = 0; j < 3; ++j) h[i][j] = H[i][j] * inv;

        // A = h^T h (symmetric PSD)
        float A[3][3];
        for (int i = 0; i < 3; ++i)
            for (int j = 0; j < 3; ++j) {
                float acc = 0.f;
                for (int m = 0; m < 3; ++m) acc += h[m][i] * h[m][j];
                A[i][j] = acc;
            }

        // Jacobi eigensolve: A = V diag(lam) V^T
        float V[3][3] = {{1.f,0.f,0.f},{0.f,1.f,0.f},{0.f,0.f,1.f}};
        const int PQ[3][2] = {{0,1},{0,2},{1,2}};
        for (int sweep = 0; sweep < 15; ++sweep) {
            for (int pi_ = 0; pi_ < 3; ++pi_) {
                const int p = PQ[pi_][0], q = PQ[pi_][1];
                const float apq = A[p][q];
                if (fabsf(apq) < 1e-20f) continue;
                const float theta = (A[q][q] - A[p][p]) / (2.f * apq);
                const float tt = copysignf(1.f, theta) /
                                 (fabsf(theta) + sqrtf(theta * theta + 1.f));
                const float c = 1.f / sqrtf(tt * tt + 1.f);
                const float sn = tt * c;
                for (int r = 0; r < 3; ++r) {
                    const float arp = A[r][p], arq = A[r][q];
                    A[r][p] = c * arp - sn * arq;
                    A[r][q] = sn * arp + c * arq;
                }
                for (int r = 0; r < 3; ++r) {
                    const float apr = A[p][r], aqr = A[q][r];
                    A[p][r] = c * apr - sn * aqr;
                    A[q][r] = sn * apr + c * aqr;
                }
                for (int r = 0; r < 3; ++r) {
                    const float vrp = V[r][p], vrq = V[r][q];
                    V[r][p] = c * vrp - sn * vrq;
                    V[r][q] = sn * vrp + c * vrq;
                }
            }
        }

        // sort eigenpairs descending (3-element sorting network)
        float lam[3] = {A[0][0], A[1][1], A[2][2]};
        for (int a2 = 0; a2 < 2; ++a2)
            for (int b2 = a2 + 1; b2 < 3; ++b2)
                if (lam[b2] > lam[a2]) {
                    float tmp = lam[a2]; lam[a2] = lam[b2]; lam[b2] = tmp;
                    for (int r = 0; r < 3; ++r) {
                        float tv2 = V[r][a2]; V[r][a2] = V[r][b2]; V[r][b2] = tv2;
                    }
                }

        // U columns: u_k = h v_k / sigma_k
        float U[3][3], sig[3];
        for (int c2 = 0; c2 < 3; ++c2) {
            float u[3];
            for (int i = 0; i < 3; ++i)
                u[i] = h[i][0] * V[0][c2] + h[i][1] * V[1][c2] + h[i][2] * V[2][c2];
            sig[c2] = sqrtf(fmaxf(u[0]*u[0] + u[1]*u[1] + u[2]*u[2], 0.f));
            const float is = 1.f / fmaxf(sig[c2], 1e-30f);
            for (int i = 0; i < 3; ++i) U[i][c2] = u[i] * is;
        }
        if (sig[2] < 1e-6f * sig[0]) {
            // smallest singular vector ill-conditioned: take cross product
            float u2[3] = {
                U[1][0] * U[2][1] - U[2][0] * U[1][1],
                U[2][0] * U[0][1] - U[0][0] * U[2][1],
                U[0][0] * U[1][1] - U[1][0] * U[0][1]};
            const float nn2 = sqrtf(u2[0]*u2[0] + u2[1]*u2[1] + u2[2]*u2[2]);
            const float is = 1.f / fmaxf(nn2, 1e-30f);
            for (int i = 0; i < 3; ++i) U[i][2] = u2[i] * is;
        }

        // det(V U^T) sign
        const float detU =
            U[0][0] * (U[1][1] * U[2][2] - U[2][1] * U[1][2]) -
            U[0][1] * (U[1][0] * U[2][2] - U[2][0] * U[1][2]) +
            U[0][2] * (U[1][0] * U[2][1] - U[2][0] * U[1][1]);
        const float detV =
            V[0][0] * (V[1][1] * V[2][2] - V[2][1] * V[1][2]) -
            V[0][1] * (V[1][0] * V[2][2] - V[2][0] * V[1][2]) +
            V[0][2] * (V[1][0] * V[2][1] - V[2][0] * V[1][1]);
        const float d = (detU * detV < 0.f) ? -1.f : 1.f;

        // R = V diag(1,1,d) U^T
        for (int i = 0; i < 3; ++i)
            for (int j = 0; j < 3; ++j)
                R_[i][j] = V[i][0] * U[j][0] + V[i][1] * U[j][1] + d * V[i][2] * U[j][2];

        tv[0] = ct0 - (R_[0][0] * cs0 + R_[0][1] * cs1 + R_[0][2] * cs2);
        tv[1] = ct1 - (R_[1][0] * cs0 + R_[1][1] * cs1 + R_[1][2] * cs2);
        tv[2] = ct2 - (R_[2][0] * cs0 + R_[2][1] * cs1 + R_[2][2] * cs2);
    }

    // Output: R (B,3,3) flat at [0,288), then t (B,3) at [288,384)
    for (int i = 0; i < 3; ++i)
        for (int j = 0; j < 3; ++j)
            out[b * 9 + i * 3 + j] = R_[i][j];
    for (int i = 0; i < 3; ++i)
        out[Bb * 9 + b * 3 + i] = tv[i];
}

extern "C" void kernel_launch(void* const* d_in, const int* in_sizes, int n_in,
                              void* d_out, int out_size, void* d_ws, size_t ws_size,
                              hipStream_t stream) {
    const float* points_x = (const float*)d_in[0];
    const float* points_y = (const float*)d_in[1];
    const float* gamma_x  = (const float*)d_in[2];
    const float* gamma_y  = (const float*)d_in[3];
    float* out = (float*)d_out;
    float4* ws4 = (float4*)d_ws;   // needs 512 * 64 * 16 B = 512 KiB

    gmm_partial_kernel<<<NBLK1, 256, 0, stream>>>(
        points_x, points_y, gamma_x, gamma_y, ws4);
    gmm_finalize_kernel<<<Bb, 64, 0, stream>>>(ws4, out);
}

// Round 2
// 310.188 us; speedup vs baseline: 1.0001x; 1.0001x over previous
//
#include <hip/hip_runtime.h>
#include <math.h>

// Problem constants (fixed by setup_inputs).
constexpr int Bb = 32;
constexpr int Nn = 16384;
constexpr int Kk = 64;
#define EPSF 1e-8f

// ---------------------------------------------------------------------------
// Kernel 1: per-chunk partial sums. Templated on chunk count so we can fall
// back to a smaller workspace footprint if ws_size is tight.
// Block = 256 threads (4 waves). Wave processes 8 consecutive rows per
// iteration (2 unrolled groups of 4): lane = sub*16 + kq; lane reads float4
// gamma[b, n, 4kq..4kq+3] -> wave reads 4 full contiguous rows (1 KiB) per
// instruction. Points for the whole chunk are staged in LDS up front, so the
// inner loop is pure gamma streaming with 2 loads in flight per lane.
// ---------------------------------------------------------------------------
template <int NCH>
__global__ __launch_bounds__(256) void gmm_partial_kernel(
    const float* __restrict__ points_x, const float* __restrict__ points_y,
    const float* __restrict__ gamma_x,  const float* __restrict__ gamma_y,
    float4* __restrict__ ws4)
{
    constexpr int ROWSC = Nn / NCH;

    const int bx    = blockIdx.x;             // 0 .. 2*Bb*NCH-1
    const int chunk = bx % NCH;
    const int combo = bx / NCH;               // 0..63
    const int s     = combo >> 5;             // set: 0=x, 1=y
    const int b     = combo & 31;

    const float* __restrict__ gbase = (s ? gamma_y : gamma_x) + (size_t)b * Nn * Kk;
    const float* __restrict__ pbase = (s ? points_y : points_x) + (size_t)b * Nn * 3;

    const int tid  = threadIdx.x;
    const int wave = tid >> 6;
    const int lane = tid & 63;
    const int sub  = lane >> 4;   // which of 4 rows this lane covers
    const int kq   = lane & 15;   // cluster quad: clusters 4kq .. 4kq+3

    const int row0 = chunk * ROWSC;

    // Stage this chunk's points into LDS (ROWSC*3 floats), coalesced float4.
    __shared__ float pts[ROWSC * 3];
    {
        const float4* __restrict__ psrc =
            reinterpret_cast<const float4*>(pbase + (size_t)row0 * 3);
        float4* pdst = reinterpret_cast<float4*>(pts);
        constexpr int NV4 = ROWSC * 3 / 4;
        for (int i = tid; i < NV4; i += 256) pdst[i] = psrc[i];
    }
    __syncthreads();

    float a0=0.f,a1=0.f,a2=0.f,a3=0.f;   // sum gamma
    float x0=0.f,x1=0.f,x2=0.f,x3=0.f;   // sum gamma*px
    float y0=0.f,y1=0.f,y2=0.f,y3=0.f;   // sum gamma*py
    float z0=0.f,z1=0.f,z2=0.f,z3=0.f;   // sum gamma*pz

    for (int r = wave * 8; r < ROWSC; r += 32) {
        const int n0 = r + sub;       // local row (unroll slot 0)
        const int n1 = r + 4 + sub;   // local row (unroll slot 1)
        // two independent 16B loads in flight
        const float4 g0 = *reinterpret_cast<const float4*>(
            gbase + (size_t)(row0 + n0) * Kk + (kq << 2));
        const float4 g1 = *reinterpret_cast<const float4*>(
            gbase + (size_t)(row0 + n1) * Kk + (kq << 2));
        const float px0 = pts[n0*3+0], py0 = pts[n0*3+1], pz0 = pts[n0*3+2];
        const float px1 = pts[n1*3+0], py1 = pts[n1*3+1], pz1 = pts[n1*3+2];

        a0 += g0.x; x0 = fmaf(g0.x, px0, x0); y0 = fmaf(g0.x, py0, y0); z0 = fmaf(g0.x, pz0, z0);
        a1 += g0.y; x1 = fmaf(g0.y, px0, x1); y1 = fmaf(g0.y, py0, y1); z1 = fmaf(g0.y, pz0, z1);
        a2 += g0.z; x2 = fmaf(g0.z, px0, x2); y2 = fmaf(g0.z, py0, y2); z2 = fmaf(g0.z, pz0, z2);
        a3 += g0.w; x3 = fmaf(g0.w, px0, x3); y3 = fmaf(g0.w, py0, y3); z3 = fmaf(g0.w, pz0, z3);

        a0 += g1.x; x0 = fmaf(g1.x, px1, x0); y0 = fmaf(g1.x, py1, y0); z0 = fmaf(g1.x, pz1, z0);
        a1 += g1.y; x1 = fmaf(g1.y, px1, x1); y1 = fmaf(g1.y, py1, y1); z1 = fmaf(g1.y, pz1, z1);
        a2 += g1.z; x2 = fmaf(g1.z, px1, x2); y2 = fmaf(g1.z, py1, y2); z2 = fmaf(g1.z, pz1, z2);
        a3 += g1.w; x3 = fmaf(g1.w, px1, x3); y3 = fmaf(g1.w, py1, y3); z3 = fmaf(g1.w, pz1, z3);
    }

    // Reduce across the 4 sub-row groups (lanes l, l^16, l^32, l^48).
#define RED2(v) { v += __shfl_xor(v, 16); v += __shfl_xor(v, 32); }
    RED2(a0) RED2(a1) RED2(a2) RED2(a3)
    RED2(x0) RED2(x1) RED2(x2) RED2(x3)
    RED2(y0) RED2(y1) RED2(y2) RED2(y3)
    RED2(z0) RED2(z1) RED2(z2) RED2(z3)
#undef RED2

    __shared__ float4 lds[4][Kk];
    if (lane < 16) {
        lds[wave][kq * 4 + 0] = make_float4(a0, x0, y0, z0);
        lds[wave][kq * 4 + 1] = make_float4(a1, x1, y1, z1);
        lds[wave][kq * 4 + 2] = make_float4(a2, x2, y2, z2);
        lds[wave][kq * 4 + 3] = make_float4(a3, x3, y3, z3);
    }
    __syncthreads();
    if (tid < Kk) {
        float4 v0 = lds[0][tid], v1 = lds[1][tid], v2 = lds[2][tid], v3 = lds[3][tid];
        float4 o;
        o.x = v0.x + v1.x + v2.x + v3.x;
        o.y = v0.y + v1.y + v2.y + v3.y;
        o.z = v0.z + v1.z + v2.z + v3.z;
        o.w = v0.w + v1.w + v2.w + v3.w;
        ws4[(size_t)bx * Kk + tid] = o;   // [(s*32+b)*NCH + chunk][k]
    }
}

// ---------------------------------------------------------------------------
// Kernel 2: per-batch finalize. 32 blocks x 64 lanes (1 wave). Lane k owns
// cluster k; wave-level butterfly reductions over K; lane 0 does the 3x3 SVD.
// ---------------------------------------------------------------------------
__device__ __forceinline__ float wred64(float v) {
    v += __shfl_xor(v, 1);  v += __shfl_xor(v, 2);  v += __shfl_xor(v, 4);
    v += __shfl_xor(v, 8);  v += __shfl_xor(v, 16); v += __shfl_xor(v, 32);
    return v;
}

__global__ __launch_bounds__(64) void gmm_finalize_kernel(
    const float4* __restrict__ ws4, float* __restrict__ out, int nchunk)
{
    const int b = blockIdx.x;   // batch
    const int k = threadIdx.x;  // cluster

    float4 s0 = make_float4(0.f, 0.f, 0.f, 0.f);
    float4 s1 = make_float4(0.f, 0.f, 0.f, 0.f);
    for (int c = 0; c < nchunk; ++c) {
        float4 t0 = ws4[((size_t)(b * nchunk + c)) * Kk + k];            // set x
        float4 t1 = ws4[((size_t)((Bb + b) * nchunk + c)) * Kk + k];     // set y
        s0.x += t0.x; s0.y += t0.y; s0.z += t0.z; s0.w += t0.w;
        s1.x += t1.x; s1.y += t1.y; s1.z += t1.z; s1.w += t1.w;
    }

    const float pix = s0.x * (1.f / Nn);
    const float piy = s1.x * (1.f / Nn);
    const float idx_ = 1.f / (pix + EPSF);
    const float idy_ = 1.f / (piy + EPSF);
    const float mux0 = s0.y * idx_, mux1 = s0.z * idx_, mux2 = s0.w * idx_;
    const float muy0 = s1.y * idy_, muy1 = s1.z * idy_, muy2 = s1.w * idy_;
    const float w = pix * piy;

    // centroid reductions
    const float wsum = wred64(w) + EPSF;
    const float cs0 = wred64(w * mux0) / wsum;
    const float cs1 = wred64(w * mux1) / wsum;
    const float cs2 = wred64(w * mux2) / wsum;
    const float ct0 = wred64(w * muy0) / wsum;
    const float ct1 = wred64(w * muy1) / wsum;
    const float ct2 = wred64(w * muy2) / wsum;

    const float sx0 = mux0 - cs0, sx1 = mux1 - cs1, sx2 = mux2 - cs2;
    const float tx0 = muy0 - ct0, tx1 = muy1 - ct1, tx2 = muy2 - ct2;

    // H_ij = sum_k w * s_i * t_j
    float H[3][3];
    H[0][0] = wred64(w * sx0 * tx0); H[0][1] = wred64(w * sx0 * tx1); H[0][2] = wred64(w * sx0 * tx2);
    H[1][0] = wred64(w * sx1 * tx0); H[1][1] = wred64(w * sx1 * tx1); H[1][2] = wred64(w * sx1 * tx2);
    H[2][0] = wred64(w * sx2 * tx0); H[2][1] = wred64(w * sx2 * tx1); H[2][2] = wred64(w * sx2 * tx2);

    if (k != 0) return;

    float R_[3][3];
    float tv[3];

    float mx = 0.f;
    for (int i = 0; i < 3; ++i)
        for (int j = 0; j < 3; ++j) mx = fmaxf(mx, fabsf(H[i][j]));

    if (mx < 1e-35f) {
        for (int i = 0; i < 3; ++i)
            for (int j = 0; j < 3; ++j) R_[i][j] = (i == j) ? 1.f : 0.f;
        tv[0] = ct0 - cs0; tv[1] = ct1 - cs1; tv[2] = ct2 - cs2;
    } else {
        const float inv = 1.f / mx;
        float h[3][3];
        for (int i = 0; i < 3; ++i)
            for (int j = 0; j < 3; ++j) h[i][j] = H[i][j] * inv;

        // A = h^T h (symmetric PSD)
        float A[3][3];
        for (int i = 0; i < 3; ++i)
            for (int j = 0; j < 3; ++j) {
                float acc = 0.f;
                for (int m = 0; m < 3; ++m) acc += h[m][i] * h[m][j];
                A[i][j] = acc;
            }

        // Jacobi eigensolve: A = V diag(lam) V^T
        float V[3][3] = {{1.f,0.f,0.f},{0.f,1.f,0.f},{0.f,0.f,1.f}};
        const int PQ[3][2] = {{0,1},{0,2},{1,2}};
        for (int sweep = 0; sweep < 15; ++sweep) {
            for (int pi_ = 0; pi_ < 3; ++pi_) {
                const int p = PQ[pi_][0], q = PQ[pi_][1];
                const float apq = A[p][q];
                if (fabsf(apq) < 1e-20f) continue;
                const float theta = (A[q][q] - A[p][p]) / (2.f * apq);
                const float tt = copysignf(1.f, theta) /
                                 (fabsf(theta) + sqrtf(theta * theta + 1.f));
                const float c = 1.f / sqrtf(tt * tt + 1.f);
                const float sn = tt * c;
                for (int r = 0; r < 3; ++r) {
                    const float arp = A[r][p], arq = A[r][q];
                    A[r][p] = c * arp - sn * arq;
                    A[r][q] = sn * arp + c * arq;
                }
                for (int r = 0; r < 3; ++r) {
                    const float apr = A[p][r], aqr = A[q][r];
                    A[p][r] = c * apr - sn * aqr;
                    A[q][r] = sn * apr + c * aqr;
                }
                for (int r = 0; r < 3; ++r) {
                    const float vrp = V[r][p], vrq = V[r][q];
                    V[r][p] = c * vrp - sn * vrq;
                    V[r][q] = sn * vrp + c * vrq;
                }
            }
        }

        // sort eigenpairs descending
        float lam[3] = {A[0][0], A[1][1], A[2][2]};
        for (int a2 = 0; a2 < 2; ++a2)
            for (int b2 = a2 + 1; b2 < 3; ++b2)
                if (lam[b2] > lam[a2]) {
                    float tmp = lam[a2]; lam[a2] = lam[b2]; lam[b2] = tmp;
                    for (int r = 0; r < 3; ++r) {
                        float tv2 = V[r][a2]; V[r][a2] = V[r][b2]; V[r][b2] = tv2;
                    }
                }

        // U columns: u_k = h v_k / sigma_k
        float U[3][3], sig[3];
        for (int c2 = 0; c2 < 3; ++c2) {
            float u[3];
            for (int i = 0; i < 3; ++i)
                u[i] = h[i][0] * V[0][c2] + h[i][1] * V[1][c2] + h[i][2] * V[2][c2];
            sig[c2] = sqrtf(fmaxf(u[0]*u[0] + u[1]*u[1] + u[2]*u[2], 0.f));
            const float is = 1.f / fmaxf(sig[c2], 1e-30f);
            for (int i = 0; i < 3; ++i) U[i][c2] = u[i] * is;
        }
        if (sig[2] < 1e-6f * sig[0]) {
            float u2[3] = {
                U[1][0] * U[2][1] - U[2][0] * U[1][1],
                U[2][0] * U[0][1] - U[0][0] * U[2][1],
                U[0][0] * U[1][1] - U[1][0] * U[0][1]};
            const float nn2 = sqrtf(u2[0]*u2[0] + u2[1]*u2[1] + u2[2]*u2[2]);
            const float is = 1.f / fmaxf(nn2, 1e-30f);
            for (int i = 0; i < 3; ++i) U[i][2] = u2[i] * is;
        }

        const float detU =
            U[0][0] * (U[1][1] * U[2][2] - U[2][1] * U[1][2]) -
            U[0][1] * (U[1][0] * U[2][2] - U[2][0] * U[1][2]) +
            U[0][2] * (U[1][0] * U[2][1] - U[2][0] * U[1][1]);
        const float detV =
            V[0][0] * (V[1][1] * V[2][2] - V[2][1] * V[1][2]) -
            V[0][1] * (V[1][0] * V[2][2] - V[2][0] * V[1][2]) +
            V[0][2] * (V[1][0] * V[2][1] - V[2][0] * V[1][1]);
        const float d = (detU * detV < 0.f) ? -1.f : 1.f;

        // R = V diag(1,1,d) U^T
        for (int i = 0; i < 3; ++i)
            for (int j = 0; j < 3; ++j)
                R_[i][j] = V[i][0] * U[j][0] + V[i][1] * U[j][1] + d * V[i][2] * U[j][2];

        tv[0] = ct0 - (R_[0][0] * cs0 + R_[0][1] * cs1 + R_[0][2] * cs2);
        tv[1] = ct1 - (R_[1][0] * cs0 + R_[1][1] * cs1 + R_[1][2] * cs2);
        tv[2] = ct2 - (R_[2][0] * cs0 + R_[2][1] * cs1 + R_[2][2] * cs2);
    }

    // Output: R (B,3,3) flat at [0,288), then t (B,3) at [288,384)
    for (int i = 0; i < 3; ++i)
        for (int j = 0; j < 3; ++j)
            out[b * 9 + i * 3 + j] = R_[i][j];
    for (int i = 0; i < 3; ++i)
        out[Bb * 9 + b * 3 + i] = tv[i];
}

extern "C" void kernel_launch(void* const* d_in, const int* in_sizes, int n_in,
                              void* d_out, int out_size, void* d_ws, size_t ws_size,
                              hipStream_t stream) {
    const float* points_x = (const float*)d_in[0];
    const float* points_y = (const float*)d_in[1];
    const float* gamma_x  = (const float*)d_in[2];
    const float* gamma_y  = (const float*)d_in[3];
    float* out = (float*)d_out;
    float4* ws4 = (float4*)d_ws;

    // Preferred: 32 chunks -> 2048 blocks (full occupancy). Needs 2 MiB ws.
    const size_t need32 = (size_t)2 * Bb * 32 * Kk * sizeof(float4);
    if (ws_size >= need32) {
        gmm_partial_kernel<32><<<2 * Bb * 32, 256, 0, stream>>>(
            points_x, points_y, gamma_x, gamma_y, ws4);
        gmm_finalize_kernel<<<Bb, 64, 0, stream>>>(ws4, out, 32);
    } else {
        gmm_partial_kernel<8><<<2 * Bb * 8, 256, 0, stream>>>(
            points_x, points_y, gamma_x, gamma_y, ws4);
        gmm_finalize_kernel<<<Bb, 64, 0, stream>>>(ws4, out, 8);
    }
}

// Round 3
// 280.462 us; speedup vs baseline: 1.1061x; 1.1060x over previous
//
#include <hip/hip_runtime.h>
#include <math.h>

// Problem constants (fixed by setup_inputs).
constexpr int Bb = 32;
constexpr int Nn = 16384;
constexpr int Kk = 64;
#define EPSF 1e-8f

typedef float f32x4 __attribute__((ext_vector_type(4)));

__device__ __forceinline__ f32x4 ntload4(const float* p) {
    return __builtin_nontemporal_load(reinterpret_cast<const f32x4*>(p));
}

// ---------------------------------------------------------------------------
// Kernel 1: per-chunk partial sums.
// Block = 256 threads (4 waves). lane = sub*16 + kq: lane reads float4
// gamma[b, n, 4kq..4kq+3]; 16 lanes with the same sub cover one full row
// (64 clusters, 256 B); the wave's 4 sub groups cover 4 contiguous rows
// (1 KiB per load instruction). Per iteration each lane issues FOUR
// independent nontemporal 16 B loads (4 KiB/wave in flight) — gamma is
// read exactly once, so nt skips L2 allocation. Points for the chunk are
// staged in LDS up front; inner loop is pure gamma streaming.
// ---------------------------------------------------------------------------
template <int NCH>
__global__ __launch_bounds__(256) void gmm_partial_kernel(
    const float* __restrict__ points_x, const float* __restrict__ points_y,
    const float* __restrict__ gamma_x,  const float* __restrict__ gamma_y,
    float4* __restrict__ ws4)
{
    constexpr int ROWSC = Nn / NCH;

    const int bx    = blockIdx.x;             // 0 .. 2*Bb*NCH-1
    const int chunk = bx % NCH;
    const int combo = bx / NCH;               // 0..63
    const int s     = combo >> 5;             // set: 0=x, 1=y
    const int b     = combo & 31;

    const float* __restrict__ gbase = (s ? gamma_y : gamma_x) + (size_t)b * Nn * Kk;
    const float* __restrict__ pbase = (s ? points_y : points_x) + (size_t)b * Nn * 3;

    const int tid  = threadIdx.x;
    const int wave = tid >> 6;
    const int lane = tid & 63;
    const int sub  = lane >> 4;   // which of 4 rows this lane covers
    const int kq   = lane & 15;   // cluster quad: clusters 4kq .. 4kq+3

    const int row0 = chunk * ROWSC;

    // Stage this chunk's points into LDS (ROWSC*3 floats), coalesced float4.
    __shared__ float pts[ROWSC * 3];
    {
        const float4* __restrict__ psrc =
            reinterpret_cast<const float4*>(pbase + (size_t)row0 * 3);
        float4* pdst = reinterpret_cast<float4*>(pts);
        constexpr int NV4 = ROWSC * 3 / 4;
        for (int i = tid; i < NV4; i += 256) pdst[i] = psrc[i];
    }
    __syncthreads();

    float a0=0.f,a1=0.f,a2=0.f,a3=0.f;   // sum gamma
    float x0=0.f,x1=0.f,x2=0.f,x3=0.f;   // sum gamma*px
    float y0=0.f,y1=0.f,y2=0.f,y3=0.f;   // sum gamma*py
    float z0=0.f,z1=0.f,z2=0.f,z3=0.f;   // sum gamma*pz

    // Wave covers 16 rows per iteration (4 unroll slots x 4 subs), block
    // covers 64 contiguous rows (16 KiB) per iteration.
    for (int r = wave * 16; r < ROWSC; r += 64) {
        const int n0 = r + sub;
        const int n1 = r + 4 + sub;
        const int n2 = r + 8 + sub;
        const int n3 = r + 12 + sub;
        const size_t kof = (size_t)(kq << 2);
        // four independent 16 B nontemporal loads in flight
        const f32x4 g0 = ntload4(gbase + (size_t)(row0 + n0) * Kk + kof);
        const f32x4 g1 = ntload4(gbase + (size_t)(row0 + n1) * Kk + kof);
        const f32x4 g2 = ntload4(gbase + (size_t)(row0 + n2) * Kk + kof);
        const f32x4 g3 = ntload4(gbase + (size_t)(row0 + n3) * Kk + kof);

        const float px0 = pts[n0*3+0], py0 = pts[n0*3+1], pz0 = pts[n0*3+2];
        const float px1 = pts[n1*3+0], py1 = pts[n1*3+1], pz1 = pts[n1*3+2];
        const float px2 = pts[n2*3+0], py2 = pts[n2*3+1], pz2 = pts[n2*3+2];
        const float px3 = pts[n3*3+0], py3 = pts[n3*3+1], pz3 = pts[n3*3+2];

        a0 += g0.x; x0 = fmaf(g0.x, px0, x0); y0 = fmaf(g0.x, py0, y0); z0 = fmaf(g0.x, pz0, z0);
        a1 += g0.y; x1 = fmaf(g0.y, px0, x1); y1 = fmaf(g0.y, py0, y1); z1 = fmaf(g0.y, pz0, z1);
        a2 += g0.z; x2 = fmaf(g0.z, px0, x2); y2 = fmaf(g0.z, py0, y2); z2 = fmaf(g0.z, pz0, z2);
        a3 += g0.w; x3 = fmaf(g0.w, px0, x3); y3 = fmaf(g0.w, py0, y3); z3 = fmaf(g0.w, pz0, z3);

        a0 += g1.x; x0 = fmaf(g1.x, px1, x0); y0 = fmaf(g1.x, py1, y0); z0 = fmaf(g1.x, pz1, z0);
        a1 += g1.y; x1 = fmaf(g1.y, px1, x1); y1 = fmaf(g1.y, py1, y1); z1 = fmaf(g1.y, pz1, z1);
        a2 += g1.z; x2 = fmaf(g1.z, px1, x2); y2 = fmaf(g1.z, py1, y2); z2 = fmaf(g1.z, pz1, z2);
        a3 += g1.w; x3 = fmaf(g1.w, px1, x3); y3 = fmaf(g1.w, py1, y3); z3 = fmaf(g1.w, pz1, z3);

        a0 += g2.x; x0 = fmaf(g2.x, px2, x0); y0 = fmaf(g2.x, py2, y0); z0 = fmaf(g2.x, pz2, z0);
        a1 += g2.y; x1 = fmaf(g2.y, px2, x1); y1 = fmaf(g2.y, py2, y1); z1 = fmaf(g2.y, pz2, z1);
        a2 += g2.z; x2 = fmaf(g2.z, px2, x2); y2 = fmaf(g2.z, py2, y2); z2 = fmaf(g2.z, pz2, z2);
        a3 += g2.w; x3 = fmaf(g2.w, px2, x3); y3 = fmaf(g2.w, py2, y3); z3 = fmaf(g2.w, pz2, z3);

        a0 += g3.x; x0 = fmaf(g3.x, px3, x0); y0 = fmaf(g3.x, py3, y0); z0 = fmaf(g3.x, pz3, z0);
        a1 += g3.y; x1 = fmaf(g3.y, px3, x1); y1 = fmaf(g3.y, py3, y1); z1 = fmaf(g3.y, pz3, z1);
        a2 += g3.z; x2 = fmaf(g3.z, px3, x2); y2 = fmaf(g3.z, py3, y2); z2 = fmaf(g3.z, pz3, z2);
        a3 += g3.w; x3 = fmaf(g3.w, px3, x3); y3 = fmaf(g3.w, py3, y3); z3 = fmaf(g3.w, pz3, z3);
    }

    // Reduce across the 4 sub-row groups (lanes l, l^16, l^32, l^48).
#define RED2(v) { v += __shfl_xor(v, 16); v += __shfl_xor(v, 32); }
    RED2(a0) RED2(a1) RED2(a2) RED2(a3)
    RED2(x0) RED2(x1) RED2(x2) RED2(x3)
    RED2(y0) RED2(y1) RED2(y2) RED2(y3)
    RED2(z0) RED2(z1) RED2(z2) RED2(z3)
#undef RED2

    __shared__ float4 lds[4][Kk];
    if (lane < 16) {
        lds[wave][kq * 4 + 0] = make_float4(a0, x0, y0, z0);
        lds[wave][kq * 4 + 1] = make_float4(a1, x1, y1, z1);
        lds[wave][kq * 4 + 2] = make_float4(a2, x2, y2, z2);
        lds[wave][kq * 4 + 3] = make_float4(a3, x3, y3, z3);
    }
    __syncthreads();
    if (tid < Kk) {
        float4 v0 = lds[0][tid], v1 = lds[1][tid], v2 = lds[2][tid], v3 = lds[3][tid];
        float4 o;
        o.x = v0.x + v1.x + v2.x + v3.x;
        o.y = v0.y + v1.y + v2.y + v3.y;
        o.z = v0.z + v1.z + v2.z + v3.z;
        o.w = v0.w + v1.w + v2.w + v3.w;
        ws4[(size_t)bx * Kk + tid] = o;   // [(s*32+b)*NCH + chunk][k]
    }
}

// ---------------------------------------------------------------------------
// Kernel 2: per-batch finalize. 32 blocks x 64 lanes (1 wave). Lane k owns
// cluster k; wave-level butterfly reductions over K; lane 0 does the 3x3 SVD.
// ---------------------------------------------------------------------------
__device__ __forceinline__ float wred64(float v) {
    v += __shfl_xor(v, 1);  v += __shfl_xor(v, 2);  v += __shfl_xor(v, 4);
    v += __shfl_xor(v, 8);  v += __shfl_xor(v, 16); v += __shfl_xor(v, 32);
    return v;
}

__global__ __launch_bounds__(64) void gmm_finalize_kernel(
    const float4* __restrict__ ws4, float* __restrict__ out, int nchunk)
{
    const int b = blockIdx.x;   // batch
    const int k = threadIdx.x;  // cluster

    float4 s0 = make_float4(0.f, 0.f, 0.f, 0.f);
    float4 s1 = make_float4(0.f, 0.f, 0.f, 0.f);
    for (int c = 0; c < nchunk; ++c) {
        float4 t0 = ws4[((size_t)(b * nchunk + c)) * Kk + k];            // set x
        float4 t1 = ws4[((size_t)((Bb + b) * nchunk + c)) * Kk + k];     // set y
        s0.x += t0.x; s0.y += t0.y; s0.z += t0.z; s0.w += t0.w;
        s1.x += t1.x; s1.y += t1.y; s1.z += t1.z; s1.w += t1.w;
    }

    const float pix = s0.x * (1.f / Nn);
    const float piy = s1.x * (1.f / Nn);
    const float idx_ = 1.f / (pix + EPSF);
    const float idy_ = 1.f / (piy + EPSF);
    const float mux0 = s0.y * idx_, mux1 = s0.z * idx_, mux2 = s0.w * idx_;
    const float muy0 = s1.y * idy_, muy1 = s1.z * idy_, muy2 = s1.w * idy_;
    const float w = pix * piy;

    // centroid reductions
    const float wsum = wred64(w) + EPSF;
    const float cs0 = wred64(w * mux0) / wsum;
    const float cs1 = wred64(w * mux1) / wsum;
    const float cs2 = wred64(w * mux2) / wsum;
    const float ct0 = wred64(w * muy0) / wsum;
    const float ct1 = wred64(w * muy1) / wsum;
    const float ct2 = wred64(w * muy2) / wsum;

    const float sx0 = mux0 - cs0, sx1 = mux1 - cs1, sx2 = mux2 - cs2;
    const float tx0 = muy0 - ct0, tx1 = muy1 - ct1, tx2 = muy2 - ct2;

    // H_ij = sum_k w * s_i * t_j
    float H[3][3];
    H[0][0] = wred64(w * sx0 * tx0); H[0][1] = wred64(w * sx0 * tx1); H[0][2] = wred64(w * sx0 * tx2);
    H[1][0] = wred64(w * sx1 * tx0); H[1][1] = wred64(w * sx1 * tx1); H[1][2] = wred64(w * sx1 * tx2);
    H[2][0] = wred64(w * sx2 * tx0); H[2][1] = wred64(w * sx2 * tx1); H[2][2] = wred64(w * sx2 * tx2);

    if (k != 0) return;

    float R_[3][3];
    float tv[3];

    float mx = 0.f;
    for (int i = 0; i < 3; ++i)
        for (int j = 0; j < 3; ++j) mx = fmaxf(mx, fabsf(H[i][j]));

    if (mx < 1e-35f) {
        for (int i = 0; i < 3; ++i)
            for (int j = 0; j < 3; ++j) R_[i][j] = (i == j) ? 1.f : 0.f;
        tv[0] = ct0 - cs0; tv[1] = ct1 - cs1; tv[2] = ct2 - cs2;
    } else {
        const float inv = 1.f / mx;
        float h[3][3];
        for (int i = 0; i < 3; ++i)
            for (int j = 0; j < 3; ++j) h[i][j] = H[i][j] * inv;

        // A = h^T h (symmetric PSD)
        float A[3][3];
        for (int i = 0; i < 3; ++i)
            for (int j = 0; j < 3; ++j) {
                float acc = 0.f;
                for (int m = 0; m < 3; ++m) acc += h[m][i] * h[m][j];
                A[i][j] = acc;
            }

        // Jacobi eigensolve: A = V diag(lam) V^T
        float V[3][3] = {{1.f,0.f,0.f},{0.f,1.f,0.f},{0.f,0.f,1.f}};
        const int PQ[3][2] = {{0,1},{0,2},{1,2}};
        for (int sweep = 0; sweep < 15; ++sweep) {
            for (int pi_ = 0; pi_ < 3; ++pi_) {
                const int p = PQ[pi_][0], q = PQ[pi_][1];
                const float apq = A[p][q];
                if (fabsf(apq) < 1e-20f) continue;
                const float theta = (A[q][q] - A[p][p]) / (2.f * apq);
                const float tt = copysignf(1.f, theta) /
                                 (fabsf(theta) + sqrtf(theta * theta + 1.f));
                const float c = 1.f / sqrtf(tt * tt + 1.f);
                const float sn = tt * c;
                for (int r = 0; r < 3; ++r) {
                    const float arp = A[r][p], arq = A[r][q];
                    A[r][p] = c * arp - sn * arq;
                    A[r][q] = sn * arp + c * arq;
                }
                for (int r = 0; r < 3; ++r) {
                    const float apr = A[p][r], aqr = A[q][r];
                    A[p][r] = c * apr - sn * aqr;
                    A[q][r] = sn * apr + c * aqr;
                }
                for (int r = 0; r < 3; ++r) {
                    const float vrp = V[r][p], vrq = V[r][q];
                    V[r][p] = c * vrp - sn * vrq;
                    V[r][q] = sn * vrp + c * vrq;
                }
            }
        }

        // sort eigenpairs descending
        float lam[3] = {A[0][0], A[1][1], A[2][2]};
        for (int a2 = 0; a2 < 2; ++a2)
            for (int b2 = a2 + 1; b2 < 3; ++b2)
                if (lam[b2] > lam[a2]) {
                    float tmp = lam[a2]; lam[a2] = lam[b2]; lam[b2] = tmp;
                    for (int r = 0; r < 3; ++r) {
                        float tv2 = V[r][a2]; V[r][a2] = V[r][b2]; V[r][b2] = tv2;
                    }
                }

        // U columns: u_k = h v_k / sigma_k
        float U[3][3], sig[3];
        for (int c2 = 0; c2 < 3; ++c2) {
            float u[3];
            for (int i = 0; i < 3; ++i)
                u[i] = h[i][0] * V[0][c2] + h[i][1] * V[1][c2] + h[i][2] * V[2][c2];
            sig[c2] = sqrtf(fmaxf(u[0]*u[0] + u[1]*u[1] + u[2]*u[2], 0.f));
            const float is = 1.f / fmaxf(sig[c2], 1e-30f);
            for (int i = 0; i < 3; ++i) U[i][c2] = u[i] * is;
        }
        if (sig[2] < 1e-6f * sig[0]) {
            float u2[3] = {
                U[1][0] * U[2][1] - U[2][0] * U[1][1],
                U[2][0] * U[0][1] - U[0][0] * U[2][1],
                U[0][0] * U[1][1] - U[1][0] * U[0][1]};
            const float nn2 = sqrtf(u2[0]*u2[0] + u2[1]*u2[1] + u2[2]*u2[2]);
            const float is = 1.f / fmaxf(nn2, 1e-30f);
            for (int i = 0; i < 3; ++i) U[i][2] = u2[i] * is;
        }

        const float detU =
            U[0][0] * (U[1][1] * U[2][2] - U[2][1] * U[1][2]) -
            U[0][1] * (U[1][0] * U[2][2] - U[2][0] * U[1][2]) +
            U[0][2] * (U[1][0] * U[2][1] - U[2][0] * U[1][1]);
        const float detV =
            V[0][0] * (V[1][1] * V[2][2] - V[2][1] * V[1][2]) -
            V[0][1] * (V[1][0] * V[2][2] - V[2][0] * V[1][2]) +
            V[0][2] * (V[1][0] * V[2][1] - V[2][0] * V[1][1]);
        const float d = (detU * detV < 0.f) ? -1.f : 1.f;

        // R = V diag(1,1,d) U^T
        for (int i = 0; i < 3; ++i)
            for (int j = 0; j < 3; ++j)
                R_[i][j] = V[i][0] * U[j][0] + V[i][1] * U[j][1] + d * V[i][2] * U[j][2];

        tv[0] = ct0 - (R_[0][0] * cs0 + R_[0][1] * cs1 + R_[0][2] * cs2);
        tv[1] = ct1 - (R_[1][0] * cs0 + R_[1][1] * cs1 + R_[1][2] * cs2);
        tv[2] = ct2 - (R_[2][0] * cs0 + R_[2][1] * cs1 + R_[2][2] * cs2);
    }

    // Output: R (B,3,3) flat at [0,288), then t (B,3) at [288,384)
    for (int i = 0; i < 3; ++i)
        for (int j = 0; j < 3; ++j)
            out[b * 9 + i * 3 + j] = R_[i][j];
    for (int i = 0; i < 3; ++i)
        out[Bb * 9 + b * 3 + i] = tv[i];
}

extern "C" void kernel_launch(void* const* d_in, const int* in_sizes, int n_in,
                              void* d_out, int out_size, void* d_ws, size_t ws_size,
                              hipStream_t stream) {
    const float* points_x = (const float*)d_in[0];
    const float* points_y = (const float*)d_in[1];
    const float* gamma_x  = (const float*)d_in[2];
    const float* gamma_y  = (const float*)d_in[3];
    float* out = (float*)d_out;
    float4* ws4 = (float4*)d_ws;

    // Preferred: 32 chunks -> 2048 blocks (full occupancy). Needs 2 MiB ws.
    const size_t need32 = (size_t)2 * Bb * 32 * Kk * sizeof(float4);
    if (ws_size >= need32) {
        gmm_partial_kernel<32><<<2 * Bb * 32, 256, 0, stream>>>(
            points_x, points_y, gamma_x, gamma_y, ws4);
        gmm_finalize_kernel<<<Bb, 64, 0, stream>>>(ws4, out, 32);
    } else {
        gmm_partial_kernel<8><<<2 * Bb * 8, 256, 0, stream>>>(
            points_x, points_y, gamma_x, gamma_y, ws4);
        gmm_finalize_kernel<<<Bb, 64, 0, stream>>>(ws4, out, 8);
    }
}